// Round 1
// baseline (108231.946 us; speedup 1.0000x reference)
//
#include <hip/hip_runtime.h>
#include <hip/hip_bf16.h>

#define L_SEQ 2048
#define HDIM 512
#define NGATE4 2048   // 4*HD
#define TAGS 48
#define START_TAG 46
#define STOP_TAG 47

// ---------------------------------------------------------------------------
// GEMM: C[M,N] = A[M,K] @ B[N,K]^T + bias1[n] (+ bias2[n])
// A rows optionally gathered: row m -> A + gather[m]*K (embedding lookup).
// f32 vector-ALU (no f32 MFMA on CDNA4). 64x64 tile, BK=32, 256 threads, 4x4/thread.
// ---------------------------------------------------------------------------
#define BM 64
#define BN 64
#define BK 32
#define LDT 68   // padded LDS row stride (floats)

__global__ __launch_bounds__(256, 2)
void gemm_abt(const float* __restrict__ A, const float* __restrict__ B,
              const float* __restrict__ bias1, const float* __restrict__ bias2,
              float* __restrict__ C, int M, int N, int K,
              const int* __restrict__ gather)
{
  __shared__ float As[BK][LDT];
  __shared__ float Bs[BK][LDT];
  const int tid = threadIdx.x;
  const int m0 = blockIdx.x * BM;
  const int n0 = blockIdx.y * BN;
  const int tm = tid >> 4, tn = tid & 15;
  const int lr = tid >> 2, lk = (tid & 3) * 8;

  float acc[4][4];
#pragma unroll
  for (int i = 0; i < 4; ++i)
#pragma unroll
    for (int c = 0; c < 4; ++c) acc[i][c] = 0.f;

  const int am = m0 + lr;
  const float* arow = gather ? (A + (size_t)gather[am] * (size_t)K)
                             : (A + (size_t)am * (size_t)K);
  const int bn = n0 + lr;
  const float* brow = B + (size_t)bn * (size_t)K;
  const bool bok = (bn < N);

  for (int kt = 0; kt < K; kt += BK) {
    const float4 a0 = *(const float4*)(arow + kt + lk);
    const float4 a1 = *(const float4*)(arow + kt + lk + 4);
    float4 b0 = make_float4(0.f, 0.f, 0.f, 0.f);
    float4 b1 = make_float4(0.f, 0.f, 0.f, 0.f);
    if (bok) {
      b0 = *(const float4*)(brow + kt + lk);
      b1 = *(const float4*)(brow + kt + lk + 4);
    }
    As[lk + 0][lr] = a0.x; As[lk + 1][lr] = a0.y; As[lk + 2][lr] = a0.z; As[lk + 3][lr] = a0.w;
    As[lk + 4][lr] = a1.x; As[lk + 5][lr] = a1.y; As[lk + 6][lr] = a1.z; As[lk + 7][lr] = a1.w;
    Bs[lk + 0][lr] = b0.x; Bs[lk + 1][lr] = b0.y; Bs[lk + 2][lr] = b0.z; Bs[lk + 3][lr] = b0.w;
    Bs[lk + 4][lr] = b1.x; Bs[lk + 5][lr] = b1.y; Bs[lk + 6][lr] = b1.z; Bs[lk + 7][lr] = b1.w;
    __syncthreads();
#pragma unroll
    for (int kk = 0; kk < BK; ++kk) {
      const float4 av = *(const float4*)&As[kk][tm * 4];
      const float4 bv = *(const float4*)&Bs[kk][tn * 4];
      const float aa[4] = {av.x, av.y, av.z, av.w};
      const float bb[4] = {bv.x, bv.y, bv.z, bv.w};
#pragma unroll
      for (int i = 0; i < 4; ++i)
#pragma unroll
        for (int c = 0; c < 4; ++c)
          acc[i][c] += aa[i] * bb[c];
    }
    __syncthreads();
  }

  float bsum[4];
#pragma unroll
  for (int c = 0; c < 4; ++c) {
    const int n = n0 + tn * 4 + c;
    float bb = 0.f;
    if (n < N) { bb = bias1[n]; if (bias2) bb += bias2[n]; }
    bsum[c] = bb;
  }
#pragma unroll
  for (int i = 0; i < 4; ++i) {
    const int m = m0 + tm * 4 + i;
#pragma unroll
    for (int c = 0; c < 4; ++c) {
      const int n = n0 + tn * 4 + c;
      if (n < N) C[(size_t)m * N + n] = acc[i][c] + bsum[c];
    }
  }
}

// ---------------------------------------------------------------------------
// Persistent bidirectional LSTM layer.
// 32 WGs x 256 threads per direction. Each WG owns 16 h-indices (64 gate rows);
// W_hh rows live in VGPRs (statically indexed after full unroll). Per step:
// dot from h_lds, shfl-reduce over 16 k-chunks, gates on leader lanes, h slice
// stored to global (device-scope atomics), counter release/acquire sync, h
// re-broadcast into LDS. dir = blockIdx%8 in {0,1} -> each direction on 1 XCD.
// ---------------------------------------------------------------------------
__global__ __launch_bounds__(256, 1)
void lstm_layer(const float* __restrict__ pre_f, const float* __restrict__ pre_r,
                const float* __restrict__ whh_f, const float* __restrict__ whh_r,
                const float* __restrict__ h0, const float* __restrict__ c0,
                int hcrow_base,
                float* __restrict__ hs_out,   // [L][1024]
                int* __restrict__ cnt)        // [2][L]
{
  const int sel = blockIdx.x & 7;
  if (sel > 1) return;
  const int dir = sel;
  const int wg = blockIdx.x >> 3;      // 0..31
  const float* pre = dir ? pre_r : pre_f;
  const float* whh = dir ? whh_r : whh_f;
  int* mycnt = cnt + dir * L_SEQ;
  const int tid = threadIdx.x;
  const int lane = tid & 63;
  const int wave = tid >> 6;
  const int q = lane & 15;             // k-chunk 0..15 (32 k each)
  const int jj = wave * 4 + (lane >> 4);
  const int j = wg * 16 + jj;          // owned h index
  const bool leader = (q == 0);
  const int hc = (hcrow_base + dir) * HDIM;

  __shared__ float h_lds[HDIM];

  // W_hh rows (i,f,g,o for h-index j) into registers; k-window rotated by q so
  // the per-step LDS reads of h land on distinct bank groups (2-way max).
  float w[4][8][4];
#pragma unroll
  for (int g = 0; g < 4; ++g) {
    const float* wr = whh + (size_t)(g * HDIM + j) * HDIM;
#pragma unroll
    for (int i = 0; i < 8; ++i) {
      const int kb = 32 * q + 4 * ((i + q) & 7);
      const float4 v = *(const float4*)(wr + kb);
      w[g][i][0] = v.x; w[g][i][1] = v.y; w[g][i][2] = v.z; w[g][i][3] = v.w;
    }
  }
  for (int i = tid; i < HDIM; i += 256) h_lds[i] = h0[hc + i];
  float cst = leader ? c0[hc + j] : 0.f;
  __syncthreads();

  // software-prefetched pre-activation values (one step ahead)
  float p[4], pn[4];
  {
    const int t0 = dir ? (L_SEQ - 1) : 0;
#pragma unroll
    for (int g = 0; g < 4; ++g)
      p[g] = leader ? pre[(size_t)t0 * NGATE4 + g * HDIM + j] : 0.f;
  }

  for (int s = 0; s < L_SEQ; ++s) {
    const int t = dir ? (L_SEQ - 1 - s) : s;
    // prefetch next step's pre rows (hidden under compute + sync)
#pragma unroll
    for (int g = 0; g < 4; ++g) pn[g] = 0.f;
    if (leader && (s + 1 < L_SEQ)) {
      const int tnx = dir ? (L_SEQ - 2 - s) : (s + 1);
#pragma unroll
      for (int g = 0; g < 4; ++g)
        pn[g] = pre[(size_t)tnx * NGATE4 + g * HDIM + j];
    }

    float a[4] = {0.f, 0.f, 0.f, 0.f};
#pragma unroll
    for (int i = 0; i < 8; ++i) {
      const int kb = 32 * q + 4 * ((i + q) & 7);
      const float4 hv = *(const float4*)&h_lds[kb];
      const float hh[4] = {hv.x, hv.y, hv.z, hv.w};
#pragma unroll
      for (int g = 0; g < 4; ++g)
#pragma unroll
        for (int c = 0; c < 4; ++c)
          a[g] += w[g][i][c] * hh[c];
    }
#pragma unroll
    for (int m = 1; m < 16; m <<= 1)
#pragma unroll
      for (int g = 0; g < 4; ++g)
        a[g] += __shfl_xor(a[g], m, 64);

    if (leader) {
      const float gi = p[0] + a[0];
      const float gf = p[1] + a[1];
      const float gg = p[2] + a[2];
      const float go = p[3] + a[3];
      const float si = 1.f / (1.f + __expf(-gi));
      const float sf = 1.f / (1.f + __expf(-gf));
      const float tg = 1.f - 2.f / (__expf(2.f * gg) + 1.f);
      const float so = 1.f / (1.f + __expf(-go));
      cst = sf * cst + si * tg;
      const float th = 1.f - 2.f / (__expf(2.f * cst) + 1.f);
      const float h = so * th;
      __hip_atomic_store(&hs_out[(size_t)t * 1024 + dir * HDIM + j], h,
                         __ATOMIC_RELAXED, __HIP_MEMORY_SCOPE_AGENT);
    }
#pragma unroll
    for (int g = 0; g < 4; ++g) p[g] = pn[g];

    if (s == L_SEQ - 1) break;

    __syncthreads();   // all h stores of this WG drained (vmcnt0 before barrier)
    if (tid == 0)
      __hip_atomic_fetch_add(&mycnt[s], 1, __ATOMIC_RELEASE, __HIP_MEMORY_SCOPE_AGENT);
    while (__hip_atomic_load(&mycnt[s], __ATOMIC_ACQUIRE, __HIP_MEMORY_SCOPE_AGENT) < 32) {
    }
    {
      const size_t base = (size_t)t * 1024 + dir * HDIM;
      const float v0 = __hip_atomic_load(&hs_out[base + tid * 2],
                                         __ATOMIC_RELAXED, __HIP_MEMORY_SCOPE_AGENT);
      const float v1 = __hip_atomic_load(&hs_out[base + tid * 2 + 1],
                                         __ATOMIC_RELAXED, __HIP_MEMORY_SCOPE_AGENT);
      h_lds[tid * 2] = v0;
      h_lds[tid * 2 + 1] = v1;
    }
    __syncthreads();
  }
}

// ---------------------------------------------------------------------------
// Viterbi: 1 WG, 192 threads = (48 tags) x (4 k-chunks of 12). Per step:
// chunk-local first-max chain, shfl argmax reduce over chunks (first-index
// tie-break matching jnp.argmax), fv via LDS. Backpointers to global ws;
// sequential backtrack at the end. Score -> out[0], path -> out[1..2048].
// ---------------------------------------------------------------------------
__global__ __launch_bounds__(192, 1)
void viterbi_kernel(const float* __restrict__ feats,
                    const float* __restrict__ trans,
                    int* __restrict__ bp,      // [L][48]
                    float* __restrict__ out)   // [1 + L]
{
  __shared__ float fv[TAGS];
  __shared__ float fvn[TAGS];
  const int tid = threadIdx.x;
  const int lane = tid & 63;
  const int wave = tid >> 6;
  const int q = lane & 3;
  const int j = wave * 16 + (lane >> 2);  // 0..47

  float trr[12];
#pragma unroll
  for (int kk = 0; kk < 12; ++kk) trr[kk] = trans[j * TAGS + q * 12 + kk];

  if (tid < TAGS) fv[tid] = (tid == START_TAG) ? 0.f : -10000.f;
  __syncthreads();

  for (int t = 0; t < L_SEQ; ++t) {
    const float ft = feats[t * TAGS + j];   // issued early, used post-reduce
    float best = -3.0e38f;
    int bi = 0;
#pragma unroll
    for (int kk = 0; kk < 12; ++kk) {
      const int k = q * 12 + kk;
      const float sc = fv[k] + trr[kk];
      if (sc > best) { best = sc; bi = k; }   // strict > keeps first max
    }
#pragma unroll
    for (int m = 1; m < 4; m <<= 1) {
      const float ov = __shfl_xor(best, m, 64);
      const int oi = __shfl_xor(bi, m, 64);
      if (ov > best || (ov == best && oi < bi)) { best = ov; bi = oi; }
    }
    __syncthreads();   // all fv reads done
    if (q == 0) {
      bp[t * TAGS + j] = bi;
      fv[j] = best + ft;
    }
    __syncthreads();
  }

  if (tid < TAGS) fvn[tid] = fv[tid] + trans[STOP_TAG * TAGS + tid];
  __syncthreads();
  if (tid == 0) {
    float best = -3.0e38f;
    int bi = 0;
    for (int k = 0; k < TAGS; ++k) {
      const float v = fvn[k];
      if (v > best) { best = v; bi = k; }
    }
    out[0] = best;
    int cur = bi;
    out[1 + (L_SEQ - 1)] = (float)cur;
    for (int t = L_SEQ - 2; t >= 0; --t) {
      cur = bp[(t + 1) * TAGS + cur];
      out[1 + t] = (float)cur;
    }
  }
}

// ---------------------------------------------------------------------------
extern "C" void kernel_launch(void* const* d_in, const int* in_sizes, int n_in,
                              void* d_out, int out_size, void* d_ws, size_t ws_size,
                              hipStream_t stream)
{
  const int*   sentence  = (const int*)  d_in[0];
  const float* embedding = (const float*)d_in[1];
  const float* w_ih_l0   = (const float*)d_in[2];
  const float* w_hh_l0   = (const float*)d_in[3];
  const float* b_ih_l0   = (const float*)d_in[4];
  const float* b_hh_l0   = (const float*)d_in[5];
  const float* w_ih_l0r  = (const float*)d_in[6];
  const float* w_hh_l0r  = (const float*)d_in[7];
  const float* b_ih_l0r  = (const float*)d_in[8];
  const float* b_hh_l0r  = (const float*)d_in[9];
  const float* w_ih_l1   = (const float*)d_in[10];
  const float* w_hh_l1   = (const float*)d_in[11];
  const float* b_ih_l1   = (const float*)d_in[12];
  const float* b_hh_l1   = (const float*)d_in[13];
  const float* w_ih_l1r  = (const float*)d_in[14];
  const float* w_hh_l1r  = (const float*)d_in[15];
  const float* b_ih_l1r  = (const float*)d_in[16];
  const float* b_hh_l1r  = (const float*)d_in[17];
  const float* h0        = (const float*)d_in[18];
  const float* c0        = (const float*)d_in[19];
  const float* W_tag     = (const float*)d_in[20];
  const float* b_tag     = (const float*)d_in[21];
  const float* trans     = (const float*)d_in[22];

  float* ws    = (float*)d_ws;
  float* pre_f = ws;                                  // [L][2048]
  float* pre_r = pre_f + (size_t)L_SEQ * NGATE4;      // [L][2048]
  float* l0out = pre_r + (size_t)L_SEQ * NGATE4;      // [L][1024]
  float* l1out = l0out + (size_t)L_SEQ * 1024;        // [L][1024]
  float* feats = l1out + (size_t)L_SEQ * 1024;        // [L][48]
  int*   cnt   = (int*)(feats + (size_t)L_SEQ * TAGS);// [4][L]
  int*   bp    = cnt + 4 * L_SEQ;                     // [L][48]

  hipMemsetAsync(cnt, 0, 4 * L_SEQ * sizeof(int), stream);

  dim3 blk(256);
  dim3 gfull(L_SEQ / BM, NGATE4 / BN);
  gemm_abt<<<gfull, blk, 0, stream>>>(embedding, w_ih_l0, b_ih_l0, b_hh_l0,
                                      pre_f, L_SEQ, NGATE4, 512, sentence);
  gemm_abt<<<gfull, blk, 0, stream>>>(embedding, w_ih_l0r, b_ih_l0r, b_hh_l0r,
                                      pre_r, L_SEQ, NGATE4, 512, sentence);
  lstm_layer<<<256, 256, 0, stream>>>(pre_f, pre_r, w_hh_l0, w_hh_l0r,
                                      h0, c0, 0, l0out, cnt);
  gemm_abt<<<gfull, blk, 0, stream>>>(l0out, w_ih_l1, b_ih_l1, b_hh_l1,
                                      pre_f, L_SEQ, NGATE4, 1024, nullptr);
  gemm_abt<<<gfull, blk, 0, stream>>>(l0out, w_ih_l1r, b_ih_l1r, b_hh_l1r,
                                      pre_r, L_SEQ, NGATE4, 1024, nullptr);
  lstm_layer<<<256, 256, 0, stream>>>(pre_f, pre_r, w_hh_l1, w_hh_l1r,
                                      h0, c0, 2, l1out, cnt + 2 * L_SEQ);
  dim3 gfeat(L_SEQ / BM, 1);
  gemm_abt<<<gfeat, blk, 0, stream>>>(l1out, W_tag, b_tag, nullptr,
                                      feats, L_SEQ, TAGS, 1024, nullptr);
  viterbi_kernel<<<1, 192, 0, stream>>>(feats, trans, bp, (float*)d_out);
}

// Round 3
// 16042.725 us; speedup vs baseline: 6.7465x; 6.7465x over previous
//
#include <hip/hip_runtime.h>
#include <hip/hip_bf16.h>

#define L_SEQ 2048
#define HDIM 512
#define NGATE4 2048   // 4*HD
#define TAGS 48
#define START_TAG 46
#define STOP_TAG 47
#define NWG 16        // workgroups per direction in lstm_layer

// ---------------------------------------------------------------------------
// GEMM: C[M,N] = A[M,K] @ B[N,K]^T + bias1[n] (+ bias2[n])
// A rows optionally gathered: row m -> A + gather[m]*K (embedding lookup).
// f32 vector-ALU (no f32 MFMA on CDNA4). 64x64 tile, BK=32, 256 threads, 4x4/thread.
// ---------------------------------------------------------------------------
#define BM 64
#define BN 64
#define BK 32
#define LDT 68   // padded LDS row stride (floats)

__global__ __launch_bounds__(256, 2)
void gemm_abt(const float* __restrict__ A, const float* __restrict__ B,
              const float* __restrict__ bias1, const float* __restrict__ bias2,
              float* __restrict__ C, int M, int N, int K,
              const int* __restrict__ gather)
{
  __shared__ float As[BK][LDT];
  __shared__ float Bs[BK][LDT];
  const int tid = threadIdx.x;
  const int m0 = blockIdx.x * BM;
  const int n0 = blockIdx.y * BN;
  const int tm = tid >> 4, tn = tid & 15;
  const int lr = tid >> 2, lk = (tid & 3) * 8;

  float acc[4][4];
#pragma unroll
  for (int i = 0; i < 4; ++i)
#pragma unroll
    for (int c = 0; c < 4; ++c) acc[i][c] = 0.f;

  const int am = m0 + lr;
  const float* arow = gather ? (A + (size_t)gather[am] * (size_t)K)
                             : (A + (size_t)am * (size_t)K);
  const int bn = n0 + lr;
  const float* brow = B + (size_t)bn * (size_t)K;
  const bool bok = (bn < N);

  for (int kt = 0; kt < K; kt += BK) {
    const float4 a0 = *(const float4*)(arow + kt + lk);
    const float4 a1 = *(const float4*)(arow + kt + lk + 4);
    float4 b0 = make_float4(0.f, 0.f, 0.f, 0.f);
    float4 b1 = make_float4(0.f, 0.f, 0.f, 0.f);
    if (bok) {
      b0 = *(const float4*)(brow + kt + lk);
      b1 = *(const float4*)(brow + kt + lk + 4);
    }
    As[lk + 0][lr] = a0.x; As[lk + 1][lr] = a0.y; As[lk + 2][lr] = a0.z; As[lk + 3][lr] = a0.w;
    As[lk + 4][lr] = a1.x; As[lk + 5][lr] = a1.y; As[lk + 6][lr] = a1.z; As[lk + 7][lr] = a1.w;
    Bs[lk + 0][lr] = b0.x; Bs[lk + 1][lr] = b0.y; Bs[lk + 2][lr] = b0.z; Bs[lk + 3][lr] = b0.w;
    Bs[lk + 4][lr] = b1.x; Bs[lk + 5][lr] = b1.y; Bs[lk + 6][lr] = b1.z; Bs[lk + 7][lr] = b1.w;
    __syncthreads();
#pragma unroll
    for (int kk = 0; kk < BK; ++kk) {
      const float4 av = *(const float4*)&As[kk][tm * 4];
      const float4 bv = *(const float4*)&Bs[kk][tn * 4];
      const float aa[4] = {av.x, av.y, av.z, av.w};
      const float bb[4] = {bv.x, bv.y, bv.z, bv.w};
#pragma unroll
      for (int i = 0; i < 4; ++i)
#pragma unroll
        for (int c = 0; c < 4; ++c)
          acc[i][c] += aa[i] * bb[c];
    }
    __syncthreads();
  }

  float bsum[4];
#pragma unroll
  for (int c = 0; c < 4; ++c) {
    const int n = n0 + tn * 4 + c;
    float bb = 0.f;
    if (n < N) { bb = bias1[n]; if (bias2) bb += bias2[n]; }
    bsum[c] = bb;
  }
#pragma unroll
  for (int i = 0; i < 4; ++i) {
    const int m = m0 + tm * 4 + i;
#pragma unroll
    for (int c = 0; c < 4; ++c) {
      const int n = n0 + tn * 4 + c;
      if (n < N) C[(size_t)m * N + n] = acc[i][c] + bsum[c];
    }
  }
}

// ---------------------------------------------------------------------------
// Persistent bidirectional LSTM layer, low-contention sync.
// 16 WGs x 512 threads per direction (grid=32). Each WG owns 32 h-indices;
// per thread: 4 gate rows x 32 k in VGPRs (128 floats, all indices static).
// Per step: LDS-dot + 16-lane shfl reduce; leaders compute gates and store h
// (relaxed agent atomics, distinct addresses); barrier (drains stores);
// tid0 release-stores a monotonic step counter into its OWN slot; wave 0
// polls the 16 slots with lane-parallel ACQUIRE loads (no same-address
// contention; acquire rides the final successful load); barrier; all 512
// threads re-load h into LDS (1 float each).
// ---------------------------------------------------------------------------
__global__ __launch_bounds__(512, 1)
void lstm_layer(const float* __restrict__ pre_f, const float* __restrict__ pre_r,
                const float* __restrict__ whh_f, const float* __restrict__ whh_r,
                const float* __restrict__ h0, const float* __restrict__ c0,
                int hcrow_base,
                float* __restrict__ hs_out,   // [L][1024]
                int* __restrict__ slots)      // [2][NWG], zeroed before launch
{
  const int dir = blockIdx.x & 1;
  const int wg  = blockIdx.x >> 1;     // 0..15
  const float* pre = dir ? pre_r : pre_f;
  const float* whh = dir ? whh_r : whh_f;
  int* myslots = slots + dir * NWG;
  const int tid = threadIdx.x;
  const int lane = tid & 63;
  const int wave = tid >> 6;
  const int q = lane & 15;                 // k-chunk 0..15 (32 k each)
  const int jj = (wave << 2) | (lane >> 4);// 0..31
  const int j = wg * 32 + jj;              // owned h index
  const bool leader = (q == 0);
  const int hc = (hcrow_base + dir) * HDIM;

  __shared__ float h_lds[HDIM];

  // W_hh rows (i,f,g,o for h-index j) into VGPRs; k-window rotated by q so
  // per-step LDS reads land 2-way max on banks (free per m136).
  float w[4][8][4];
#pragma unroll
  for (int g = 0; g < 4; ++g) {
    const float* wr = whh + (size_t)(g * HDIM + j) * HDIM;
#pragma unroll
    for (int i = 0; i < 8; ++i) {
      const int kb = 32 * q + 4 * ((i + q) & 7);
      const float4 v = *(const float4*)(wr + kb);
      w[g][i][0] = v.x; w[g][i][1] = v.y; w[g][i][2] = v.z; w[g][i][3] = v.w;
    }
  }
  h_lds[tid] = h0[hc + tid];               // blockDim == HDIM
  float cst = leader ? c0[hc + j] : 0.f;
  __syncthreads();

  // software-prefetched pre-activation values (one step ahead)
  float p[4], pn[4];
  {
    const int t0 = dir ? (L_SEQ - 1) : 0;
#pragma unroll
    for (int g = 0; g < 4; ++g)
      p[g] = leader ? pre[(size_t)t0 * NGATE4 + g * HDIM + j] : 0.f;
  }

  for (int s = 0; s < L_SEQ; ++s) {
    const int t = dir ? (L_SEQ - 1 - s) : s;
    // prefetch next step's pre rows (hidden under compute + sync)
#pragma unroll
    for (int g = 0; g < 4; ++g) pn[g] = 0.f;
    if (leader && (s + 1 < L_SEQ)) {
      const int tnx = dir ? (L_SEQ - 2 - s) : (s + 1);
#pragma unroll
      for (int g = 0; g < 4; ++g)
        pn[g] = pre[(size_t)tnx * NGATE4 + g * HDIM + j];
    }

    float a[4] = {0.f, 0.f, 0.f, 0.f};
#pragma unroll
    for (int i = 0; i < 8; ++i) {
      const int kb = 32 * q + 4 * ((i + q) & 7);
      const float4 hv = *(const float4*)&h_lds[kb];
      const float hh[4] = {hv.x, hv.y, hv.z, hv.w};
#pragma unroll
      for (int g = 0; g < 4; ++g)
#pragma unroll
        for (int c = 0; c < 4; ++c)
          a[g] += w[g][i][c] * hh[c];
    }
#pragma unroll
    for (int m = 1; m < 16; m <<= 1)
#pragma unroll
      for (int g = 0; g < 4; ++g)
        a[g] += __shfl_xor(a[g], m, 64);

    if (leader) {
      const float gi = p[0] + a[0];
      const float gf = p[1] + a[1];
      const float gg = p[2] + a[2];
      const float go = p[3] + a[3];
      const float si = 1.f / (1.f + __expf(-gi));
      const float sf = 1.f / (1.f + __expf(-gf));
      const float tg = 1.f - 2.f / (__expf(2.f * gg) + 1.f);
      const float so = 1.f / (1.f + __expf(-go));
      cst = sf * cst + si * tg;
      const float th = 1.f - 2.f / (__expf(2.f * cst) + 1.f);
      const float h = so * th;
      __hip_atomic_store(&hs_out[(size_t)t * 1024 + dir * HDIM + j], h,
                         __ATOMIC_RELAXED, __HIP_MEMORY_SCOPE_AGENT);
    }
#pragma unroll
    for (int g = 0; g < 4; ++g) p[g] = pn[g];

    if (s == L_SEQ - 1) break;

    __syncthreads();   // drains this WG's h stores (vmcnt0 before barrier)
    if (tid == 0)
      __hip_atomic_store(&myslots[wg], s + 1, __ATOMIC_RELEASE,
                         __HIP_MEMORY_SCOPE_AGENT);
    if (wave == 0) {
      for (;;) {
        const int v = (lane < NWG)
            ? __hip_atomic_load(&myslots[lane], __ATOMIC_ACQUIRE,
                                __HIP_MEMORY_SCOPE_AGENT)
            : 0x7fffffff;
        if (__all(v > s)) break;
      }
    }
    __syncthreads();
    {
      const size_t base = (size_t)t * 1024 + dir * HDIM;
      h_lds[tid] = __hip_atomic_load(&hs_out[base + tid], __ATOMIC_RELAXED,
                                     __HIP_MEMORY_SCOPE_AGENT);
    }
    __syncthreads();
  }
}

// ---------------------------------------------------------------------------
// Viterbi: 1 WG, 192 threads = (48 tags) x (4 k-chunks of 12). Per step:
// chunk-local first-max chain, shfl argmax reduce over chunks (first-index
// tie-break matching jnp.argmax), fv via LDS. Backpointers to global ws;
// sequential backtrack at the end. Score -> out[0], path -> out[1..2048].
// ---------------------------------------------------------------------------
__global__ __launch_bounds__(192, 1)
void viterbi_kernel(const float* __restrict__ feats,
                    const float* __restrict__ trans,
                    int* __restrict__ bp,      // [L][48]
                    float* __restrict__ out)   // [1 + L]
{
  __shared__ float fv[TAGS];
  __shared__ float fvn[TAGS];
  const int tid = threadIdx.x;
  const int lane = tid & 63;
  const int wave = tid >> 6;
  const int q = lane & 3;
  const int j = wave * 16 + (lane >> 2);  // 0..47

  float trr[12];
#pragma unroll
  for (int kk = 0; kk < 12; ++kk) trr[kk] = trans[j * TAGS + q * 12 + kk];

  if (tid < TAGS) fv[tid] = (tid == START_TAG) ? 0.f : -10000.f;
  __syncthreads();

  for (int t = 0; t < L_SEQ; ++t) {
    const float ft = feats[t * TAGS + j];   // issued early, used post-reduce
    float best = -3.0e38f;
    int bi = 0;
#pragma unroll
    for (int kk = 0; kk < 12; ++kk) {
      const int k = q * 12 + kk;
      const float sc = fv[k] + trr[kk];
      if (sc > best) { best = sc; bi = k; }   // strict > keeps first max
    }
#pragma unroll
    for (int m = 1; m < 4; m <<= 1) {
      const float ov = __shfl_xor(best, m, 64);
      const int oi = __shfl_xor(bi, m, 64);
      if (ov > best || (ov == best && oi < bi)) { best = ov; bi = oi; }
    }
    __syncthreads();   // all fv reads done
    if (q == 0) {
      bp[t * TAGS + j] = bi;
      fv[j] = best + ft;
    }
    __syncthreads();
  }

  if (tid < TAGS) fvn[tid] = fv[tid] + trans[STOP_TAG * TAGS + tid];
  __syncthreads();
  if (tid == 0) {
    float best = -3.0e38f;
    int bi = 0;
    for (int k = 0; k < TAGS; ++k) {
      const float v = fvn[k];
      if (v > best) { best = v; bi = k; }
    }
    out[0] = best;
    int cur = bi;
    out[1 + (L_SEQ - 1)] = (float)cur;
    for (int t = L_SEQ - 2; t >= 0; --t) {
      cur = bp[(t + 1) * TAGS + cur];
      out[1 + t] = (float)cur;
    }
  }
}

// ---------------------------------------------------------------------------
extern "C" void kernel_launch(void* const* d_in, const int* in_sizes, int n_in,
                              void* d_out, int out_size, void* d_ws, size_t ws_size,
                              hipStream_t stream)
{
  const int*   sentence  = (const int*)  d_in[0];
  const float* embedding = (const float*)d_in[1];
  const float* w_ih_l0   = (const float*)d_in[2];
  const float* w_hh_l0   = (const float*)d_in[3];
  const float* b_ih_l0   = (const float*)d_in[4];
  const float* b_hh_l0   = (const float*)d_in[5];
  const float* w_ih_l0r  = (const float*)d_in[6];
  const float* w_hh_l0r  = (const float*)d_in[7];
  const float* b_ih_l0r  = (const float*)d_in[8];
  const float* b_hh_l0r  = (const float*)d_in[9];
  const float* w_ih_l1   = (const float*)d_in[10];
  const float* w_hh_l1   = (const float*)d_in[11];
  const float* b_ih_l1   = (const float*)d_in[12];
  const float* b_hh_l1   = (const float*)d_in[13];
  const float* w_ih_l1r  = (const float*)d_in[14];
  const float* w_hh_l1r  = (const float*)d_in[15];
  const float* b_ih_l1r  = (const float*)d_in[16];
  const float* b_hh_l1r  = (const float*)d_in[17];
  const float* h0        = (const float*)d_in[18];
  const float* c0        = (const float*)d_in[19];
  const float* W_tag     = (const float*)d_in[20];
  const float* b_tag     = (const float*)d_in[21];
  const float* trans     = (const float*)d_in[22];

  float* ws    = (float*)d_ws;
  float* pre_f = ws;                                  // [L][2048]
  float* pre_r = pre_f + (size_t)L_SEQ * NGATE4;      // [L][2048]
  float* l0out = pre_r + (size_t)L_SEQ * NGATE4;      // [L][1024]
  float* l1out = l0out + (size_t)L_SEQ * 1024;        // [L][1024]
  float* feats = l1out + (size_t)L_SEQ * 1024;        // [L][48]
  int*   slots = (int*)(feats + (size_t)L_SEQ * TAGS);// [2 layers][2][NWG]
  int*   bp    = slots + 4 * NWG;                     // [L][48]

  (void)hipMemsetAsync(slots, 0, 4 * NWG * sizeof(int), stream);

  dim3 blk(256);
  dim3 gfull(L_SEQ / BM, NGATE4 / BN);
  gemm_abt<<<gfull, blk, 0, stream>>>(embedding, w_ih_l0, b_ih_l0, b_hh_l0,
                                      pre_f, L_SEQ, NGATE4, 512, sentence);
  gemm_abt<<<gfull, blk, 0, stream>>>(embedding, w_ih_l0r, b_ih_l0r, b_hh_l0r,
                                      pre_r, L_SEQ, NGATE4, 512, sentence);
  lstm_layer<<<2 * NWG, 512, 0, stream>>>(pre_f, pre_r, w_hh_l0, w_hh_l0r,
                                          h0, c0, 0, l0out, slots);
  gemm_abt<<<gfull, blk, 0, stream>>>(l0out, w_ih_l1, b_ih_l1, b_hh_l1,
                                      pre_f, L_SEQ, NGATE4, 1024, nullptr);
  gemm_abt<<<gfull, blk, 0, stream>>>(l0out, w_ih_l1r, b_ih_l1r, b_hh_l1r,
                                      pre_r, L_SEQ, NGATE4, 1024, nullptr);
  lstm_layer<<<2 * NWG, 512, 0, stream>>>(pre_f, pre_r, w_hh_l1, w_hh_l1r,
                                          h0, c0, 2, l1out, slots + 2 * NWG);
  dim3 gfeat(L_SEQ / BM, 1);
  gemm_abt<<<gfeat, blk, 0, stream>>>(l1out, W_tag, b_tag, nullptr,
                                      feats, L_SEQ, TAGS, 1024, nullptr);
  viterbi_kernel<<<1, 192, 0, stream>>>(feats, trans, bp, (float*)d_out);
}